// Round 1
// baseline (3952.489 us; speedup 1.0000x reference)
//
#include <hip/hip_runtime.h>
#include <math.h>

typedef unsigned long long u64;

#define MAXS 16
#define NB 4
#define IH 720
#define IW 1280
#define OFFC 5120.0f   // 4.0 * max(h,w)
#define KG 2048

// ---------------- shared host/device structs ----------------
struct SInfo {
  int oh, ow, hp, wp, h2, w2, hc, wc, n, k;
  float scf;
  int img_off, pool_off, c2_off, nk_off, cand_base;
};
struct PAll {
  SInfo s[MAXS];
  int blkR[MAXS+1], blkC1[MAXS+1], blkC2[MAXS+1], blkH[MAXS+1];
  int ns;
};
struct RedEnt { int in_buf, blk_start, nblk, in_off, out_off, n; };
struct RedArgs { RedEnt e[MAXS]; int ne, outk; };
struct FinEnt { int in_buf, in_off, n, k, hc, wc, cand_base, nk_off; float scf; };
struct FinArgs { FinEnt e[MAXS]; };
struct NmsArgs { int base[MAXS], kk[MAXS]; };

// ---------------- key helpers: total order matching lax.top_k ----------------
// composite = (monotonic(u32 of value) << 32) | ~idx  -> sort descending gives
// value desc, ties by index asc (exactly lax.top_k). Pad value 0 sorts below all
// real keys (even -inf keys map to 0x007FFFFF........ > 0).
__device__ __forceinline__ u64 makekey(float v, unsigned idx) {
  unsigned b = __float_as_uint(v);
  unsigned u = (b & 0x80000000u) ? ~b : (b | 0x80000000u);
  return ((u64)u << 32) | (unsigned)(~idx);
}
__device__ __forceinline__ float keyval(u64 c) {
  unsigned u = (unsigned)(c >> 32);
  unsigned b = (u & 0x80000000u) ? (u ^ 0x80000000u) : ~u;
  return __uint_as_float(b);
}

// ---------------- 1. area resize + normalize ----------------
__global__ __launch_bounds__(256) void k_resize(const float* __restrict__ img,
                                                float* __restrict__ out, PAll P) {
  int blk = blockIdx.x, si = 0;
  while (si + 1 < P.ns && blk >= P.blkR[si+1]) ++si;
  SInfo S = P.s[si];
  int local = (blk - P.blkR[si]) * 256 + threadIdx.x;
  int total = NB*3*S.oh*S.ow;
  if (local >= total) return;
  int x = local % S.ow; int t = local / S.ow;
  int y = t % S.oh; t /= S.oh;
  int c = t % 3; int b = t / 3;
  int hs = (y*IH)/S.oh, he = ((y+1)*IH + S.oh - 1)/S.oh;
  int ws = (x*IW)/S.ow, we = ((x+1)*IW + S.ow - 1)/S.ow;
  float rh = 1.0f/(float)(he-hs), rw = 1.0f/(float)(we-ws);
  const float* bp = img + (size_t)(b*3+c)*IH*IW;
  float acc = 0.f;
  for (int xx = ws; xx < we; ++xx) {
    float cs = 0.f;
    for (int yy = hs; yy < he; ++yy) cs += bp[yy*IW + xx] * rh;   // rows first (Mh)
    acc += cs * rw;                                               // then cols (Mw)
  }
  out[S.img_off + local] = (acc - 127.5f) * 0.0078125f;
}

// ---------------- 2. conv1(3x3,10ch) + PReLU + ceil-maxpool2 (fused) ----------------
__global__ __launch_bounds__(256) void k_conv1pool(const float* __restrict__ rsz,
    const float* __restrict__ w1, const float* __restrict__ b1, const float* __restrict__ a1,
    float* __restrict__ pool, PAll P) {
  int blk = blockIdx.x, si = 0;
  while (si + 1 < P.ns && blk >= P.blkC1[si+1]) ++si;
  SInfo S = P.s[si];
  int local = (blk - P.blkC1[si]) * 256 + threadIdx.x;
  int total = NB*10*S.hp*S.wp;
  if (local >= total) return;
  int x = local % S.wp; int t = local / S.wp;
  int y = t % S.hp; t /= S.hp;
  int o = t % 10; int b = t / 10;
  int H1 = S.oh - 2, W1 = S.ow - 2;
  float m = -INFINITY;
  for (int dy = 0; dy < 2; ++dy) {
    int ry = 2*y + dy; if (ry >= H1) continue;
    for (int dx = 0; dx < 2; ++dx) {
      int rx = 2*x + dx; if (rx >= W1) continue;
      float v = 0.f;
      for (int c = 0; c < 3; ++c) {
        const float* ip = rsz + S.img_off + ((b*3 + c)*S.oh + ry)*S.ow + rx;
        #pragma unroll
        for (int ky = 0; ky < 3; ++ky)
          #pragma unroll
          for (int kx = 0; kx < 3; ++kx)
            v += ip[ky*S.ow + kx] * w1[((o*3 + c)*3 + ky)*3 + kx];
      }
      v += b1[o];
      v = v > 0.f ? v : a1[o]*v;
      m = fmaxf(m, v);
    }
  }
  pool[S.pool_off + local] = m;
}

// ---------------- 3. conv2(3x3,16ch) + PReLU ----------------
__global__ __launch_bounds__(256) void k_conv2(const float* __restrict__ pool,
    const float* __restrict__ w2, const float* __restrict__ b2w, const float* __restrict__ a2,
    float* __restrict__ c2o, PAll P) {
  int blk = blockIdx.x, si = 0;
  while (si + 1 < P.ns && blk >= P.blkC2[si+1]) ++si;
  SInfo S = P.s[si];
  int local = (blk - P.blkC2[si]) * 256 + threadIdx.x;
  int total = NB*16*S.h2*S.w2;
  if (local >= total) return;
  int x = local % S.w2; int t = local / S.w2;
  int y = t % S.h2; t /= S.h2;
  int o = t % 16; int b = t / 16;
  float v = 0.f;
  for (int c = 0; c < 10; ++c) {
    const float* ip = pool + S.pool_off + ((b*10 + c)*S.hp + y)*S.wp + x;
    #pragma unroll
    for (int ky = 0; ky < 3; ++ky)
      #pragma unroll
      for (int kx = 0; kx < 3; ++kx)
        v += ip[ky*S.wp + kx] * w2[((o*10 + c)*3 + ky)*3 + kx];
  }
  v += b2w[o];
  v = v > 0.f ? v : a2[o]*v;
  c2o[S.c2_off + local] = v;
}

// ---------------- 4. conv3(3x3,32ch)+PReLU + 1x1 heads + softmax + key/reg emit ----------------
__global__ __launch_bounds__(256) void k_conv3heads(const float* __restrict__ c2,
    const float* __restrict__ w3, const float* __restrict__ b3, const float* __restrict__ a3,
    const float* __restrict__ w41, const float* __restrict__ b41,
    const float* __restrict__ w42, const float* __restrict__ b42,
    u64* __restrict__ keys, float4* __restrict__ reg4, PAll P) {
  int blk = blockIdx.x, si = 0;
  while (si + 1 < P.ns && blk >= P.blkH[si+1]) ++si;
  SInfo S = P.s[si];
  int local = (blk - P.blkH[si]) * 256 + threadIdx.x;
  if (local >= S.n) return;
  int x = local % S.wc; int t = local / S.wc;
  int y = t % S.hc; int b = t / S.hc;
  float acc[32];
  #pragma unroll
  for (int oc = 0; oc < 32; ++oc) acc[oc] = 0.f;
  int chs = S.h2 * S.w2;
  for (int ky = 0; ky < 3; ++ky)
    for (int kx = 0; kx < 3; ++kx) {
      const float* ip = c2 + S.c2_off + ((b*16)*S.h2 + (y+ky))*S.w2 + (x+kx);
      float v[16];
      #pragma unroll
      for (int ic = 0; ic < 16; ++ic) v[ic] = ip[ic*chs];
      #pragma unroll
      for (int oc = 0; oc < 32; ++oc) {
        float tt = 0.f;
        #pragma unroll
        for (int ic = 0; ic < 16; ++ic)
          tt += v[ic] * w3[((oc*16 + ic)*3 + ky)*3 + kx];   // uniform addr -> s_load
        acc[oc] += tt;
      }
    }
  float l0 = 0.f, l1 = 0.f, r0 = 0.f, r1 = 0.f, r2 = 0.f, r3 = 0.f;
  #pragma unroll
  for (int oc = 0; oc < 32; ++oc) {
    float vv = acc[oc] + b3[oc];
    vv = vv > 0.f ? vv : a3[oc]*vv;
    l0 += vv * w41[oc];      l1 += vv * w41[32 + oc];
    r0 += vv * w42[oc];      r1 += vv * w42[32 + oc];
    r2 += vv * w42[64 + oc]; r3 += vv * w42[96 + oc];
  }
  l0 += b41[0]; l1 += b41[1];
  r0 += b42[0]; r1 += b42[1]; r2 += b42[2]; r3 += b42[3];
  float mx = fmaxf(l0, l1);
  float e0 = expf(l0 - mx), e1 = expf(l1 - mx);
  float score = e1 / (e0 + e1);
  float kv = (score >= 0.6f) ? score : -INFINITY;
  keys[S.nk_off + local] = makekey(kv, (unsigned)local);
  reg4[S.nk_off + local] = make_float4(r0, r1, r2, r3);
}

// ---------------- bitonic sort (4096, descending) in LDS ----------------
__device__ inline void bitonic4096_desc(u64* sh) {
  for (int kk = 2; kk <= 4096; kk <<= 1)
    for (int j = kk >> 1; j > 0; j >>= 1) {
      __syncthreads();
      for (int i = threadIdx.x; i < 4096; i += 256) {
        int ixj = i ^ j;
        if (ixj > i) {
          u64 a = sh[i], b = sh[ixj];
          if (((i & kk) == 0) ? (a < b) : (a > b)) { sh[i] = b; sh[ixj] = a; }
        }
      }
    }
  __syncthreads();
}

// ---------------- 5. hierarchical top-k reduce ----------------
__global__ __launch_bounds__(256) void k_topk_reduce(const u64* __restrict__ b0,
    const u64* __restrict__ b1, const u64* __restrict__ b2, const u64* __restrict__ b3,
    u64* __restrict__ outb, RedArgs ra) {
  __shared__ u64 sh[4096];
  int blk = blockIdx.x, ei = 0;
  while (ei + 1 < ra.ne && blk >= ra.e[ei].blk_start + ra.e[ei].nblk) ++ei;
  RedEnt e = ra.e[ei];
  int chunk = blk - e.blk_start;
  const u64* in = (e.in_buf == 0 ? b0 : e.in_buf == 1 ? b1 : e.in_buf == 2 ? b2 : b3)
                  + e.in_off + (size_t)chunk*4096;
  int m = e.n - chunk*4096; if (m > 4096) m = 4096;
  for (int i = threadIdx.x; i < 4096; i += 256) sh[i] = (i < m) ? in[i] : 0ULL;
  bitonic4096_desc(sh);
  u64* o = outb + e.out_off + (size_t)chunk * ra.outk;
  for (int i = threadIdx.x; i < ra.outk; i += 256) o[i] = sh[i];
}

// ---------------- 6. final per-scale sort + candidate gather ----------------
__global__ __launch_bounds__(256) void k_final_gather(const u64* __restrict__ b0,
    const u64* __restrict__ b1, const u64* __restrict__ b2,
    const float4* __restrict__ reg4, float* __restrict__ cb9, int* __restrict__ cinds,
    FinArgs fa) {
  __shared__ u64 sh[4096];
  FinEnt f = fa.e[blockIdx.x];
  const u64* in = (f.in_buf == 0 ? b0 : f.in_buf == 1 ? b1 : b2) + f.in_off;
  for (int i = threadIdx.x; i < 4096; i += 256) sh[i] = (i < f.n) ? in[i] : 0ULL;
  bitonic4096_desc(sh);
  for (int i = threadIdx.x; i < f.k; i += 256) {
    u64 c = sh[i];
    float val = keyval(c);
    unsigned idx = ~(unsigned)c;
    int x = (int)(idx % (unsigned)f.wc); unsigned t2 = idx / (unsigned)f.wc;
    int y = (int)(t2 % (unsigned)f.hc); int b = (int)(t2 / (unsigned)f.hc);
    float cx = (float)x, cy = (float)y;
    float x1 = floorf((2.0f*cx + 1.0f)/f.scf);
    float y1 = floorf((2.0f*cy + 1.0f)/f.scf);
    float x2 = floorf((2.0f*cx + 12.0f)/f.scf);
    float y2 = floorf((2.0f*cy + 12.0f)/f.scf);
    float4 rg = reg4[f.nk_off + idx];
    int g = f.cand_base + i;
    float* p = cb9 + (size_t)g*9;
    p[0]=x1; p[1]=y1; p[2]=x2; p[3]=y2; p[4]=val;
    p[5]=rg.x; p[6]=rg.y; p[7]=rg.z; p[8]=rg.w;
    cinds[g] = b;
  }
}

// ---------------- 7. per-scale greedy NMS (1 wave / scale), writes global keys ----------------
__global__ __launch_bounds__(64) void k_nms_scale(const float* __restrict__ cb9,
    const int* __restrict__ cinds, u64* __restrict__ candk, NmsArgs na) {
  __shared__ float sx1[1024], sy1[1024], sx2[1024], sy2[1024], sar[1024], ssc[1024];
  int s = blockIdx.x, base = na.base[s], k = na.kk[s];
  int lane = threadIdx.x;
  for (int j = lane; j < k; j += 64) {
    const float* p = cb9 + (size_t)(base + j)*9;
    float off = OFFC * (float)cinds[base + j];
    float a = p[0] + off, b = p[1] + off, c = p[2] + off, d = p[3] + off;
    sx1[j]=a; sy1[j]=b; sx2[j]=c; sy2[j]=d;
    sar[j] = (c - a + 1.0f) * (d - b + 1.0f);
    ssc[j] = p[4];
  }
  __syncthreads();
  unsigned sup = 0, kept = 0;
  for (int i = 0; i < k; ++i) {
    int owner = i & 63, bit = i >> 6;
    unsigned so = (unsigned)__shfl((int)sup, owner);
    bool keep_i = (ssc[i] != -INFINITY) && !((so >> bit) & 1u);
    if (keep_i) {
      if (lane == owner) kept |= 1u << bit;
      float xi1 = sx1[i], yi1 = sy1[i], xi2 = sx2[i], yi2 = sy2[i], ai = sar[i];
      #pragma unroll
      for (int t = 0; t < 16; ++t) {
        int j = t*64 + lane;
        if (j > i && j < k) {
          float iw = fminf(xi2, sx2[j]) - fmaxf(xi1, sx1[j]) + 1.0f; iw = fmaxf(iw, 0.0f);
          float ih = fminf(yi2, sy2[j]) - fmaxf(yi1, sy1[j]) + 1.0f; ih = fmaxf(ih, 0.0f);
          float inter = iw*ih;
          if (inter / (ai + sar[j] - inter) > 0.5f) sup |= 1u << t;
        }
      }
    }
  }
  for (int t = 0; t < 16; ++t) {
    int j = t*64 + lane;
    if (j < k) {
      float v = ((kept >> t) & 1u) ? ssc[j] : -INFINITY;
      candk[base + j] = makekey(v, (unsigned)(base + j));
    }
  }
}

// ---------------- 8. global final sort (4096 -> top 2048) ----------------
__global__ __launch_bounds__(256) void k_gfinal(const u64* __restrict__ in, u64* __restrict__ gs) {
  __shared__ u64 sh[4096];
  for (int i = threadIdx.x; i < 4096; i += 256) sh[i] = in[i];
  bitonic4096_desc(sh);
  for (int i = threadIdx.x; i < KG; i += 256) gs[i] = sh[i];
}

// ---------------- 9. global greedy NMS (thresh 0.7) ----------------
__global__ __launch_bounds__(64) void k_nms_global(const u64* __restrict__ gs,
    const float* __restrict__ cb9, const int* __restrict__ cinds, int* __restrict__ gkeep) {
  __shared__ float sx1[KG], sy1[KG], sx2[KG], sy2[KG], sar[KG], ssc[KG];
  int lane = threadIdx.x;
  for (int j = lane; j < KG; j += 64) {
    u64 c = gs[j];
    unsigned g = ~(unsigned)c;
    const float* p = cb9 + (size_t)g*9;
    float off = OFFC * (float)cinds[g];
    float a = p[0] + off, b = p[1] + off, cc = p[2] + off, d = p[3] + off;
    sx1[j]=a; sy1[j]=b; sx2[j]=cc; sy2[j]=d;
    sar[j] = (cc - a + 1.0f) * (d - b + 1.0f);
    ssc[j] = keyval(c);
  }
  __syncthreads();
  unsigned sup = 0, kept = 0;
  for (int i = 0; i < KG; ++i) {
    int owner = i & 63, bit = i >> 6;
    unsigned so = (unsigned)__shfl((int)sup, owner);
    bool keep_i = (ssc[i] != -INFINITY) && !((so >> bit) & 1u);
    if (keep_i) {
      if (lane == owner) kept |= 1u << bit;
      float xi1 = sx1[i], yi1 = sy1[i], xi2 = sx2[i], yi2 = sy2[i], ai = sar[i];
      #pragma unroll
      for (int t = 0; t < 32; ++t) {
        int j = t*64 + lane;
        if (j > i) {
          float iw = fminf(xi2, sx2[j]) - fmaxf(xi1, sx1[j]) + 1.0f; iw = fmaxf(iw, 0.0f);
          float ih = fminf(yi2, sy2[j]) - fmaxf(yi1, sy1[j]) + 1.0f; ih = fmaxf(ih, 0.0f);
          float inter = iw*ih;
          if (inter / (ai + sar[j] - inter) > 0.7f) sup |= 1u << t;
        }
      }
    }
  }
  for (int t = 0; t < 32; ++t) { int j = t*64 + lane; gkeep[j] = (int)((kept >> t) & 1u); }
}

// ---------------- 10. refinement + output ----------------
__global__ __launch_bounds__(256) void k_finalize(const u64* __restrict__ gs,
    const int* __restrict__ gkeep, const float* __restrict__ cb9, const int* __restrict__ cinds,
    float* __restrict__ out) {
  int r = blockIdx.x*256 + threadIdx.x;
  if (r >= KG) return;
  u64 c = gs[r];
  unsigned g = ~(unsigned)c;
  float val = keyval(c);
  const float* p = cb9 + (size_t)g*9;
  int ind = cinds[g];
  bool valid = (val != -INFINITY) && (gkeep[r] != 0);
  float b0=p[0], b1v=p[1], b2v=p[2], b3=p[3], sc=p[4], r5=p[5], r6=p[6], r7=p[7], r8=p[8];
  float regw = b2v - b0, regh = b3 - b1v;
  float qq1 = b0 + r5*regw, qq2 = b1v + r6*regh, qq3 = b2v + r7*regw, qq4 = b3 + r8*regh;
  float bw = qq3 - qq1, bh = qq4 - qq2;
  float l = fmaxf(bw, bh);
  float x1n = qq1 + bw*0.5f - l*0.5f;
  float y1n = qq2 + bh*0.5f - l*0.5f;
  float o0 = x1n, o1 = y1n, o2 = x1n + l, o3 = y1n + l, o4 = sc;
  if (!valid) { o0=o1=o2=o3=o4=0.f; }
  out[r*5+0]=o0; out[r*5+1]=o1; out[r*5+2]=o2; out[r*5+3]=o3; out[r*5+4]=o4;
  out[5*KG + r] = valid ? 1.0f : 0.0f;
  out[6*KG + r] = (float)ind;
}

// ---------------- host ----------------
extern "C" void kernel_launch(void* const* d_in, const int* in_sizes, int n_in,
                              void* d_out, int out_size, void* d_ws, size_t ws_size,
                              hipStream_t stream) {
  (void)in_sizes; (void)n_in; (void)out_size;
  const float* imgs = (const float*)d_in[0];
  const float* c1w  = (const float*)d_in[1];
  const float* c1b  = (const float*)d_in[2];
  const float* a1   = (const float*)d_in[3];
  const float* c2w  = (const float*)d_in[4];
  const float* c2b  = (const float*)d_in[5];
  const float* a2   = (const float*)d_in[6];
  const float* c3w  = (const float*)d_in[7];
  const float* c3b  = (const float*)d_in[8];
  const float* a3   = (const float*)d_in[9];
  const float* c41w = (const float*)d_in[10];
  const float* c41b = (const float*)d_in[11];
  const float* c42w = (const float*)d_in[12];
  const float* c42b = (const float*)d_in[13];
  float* out = (float*)d_out;

  // scale pyramid, exactly mirroring the Python double-precision loop
  int ns = 0; double scl[MAXS];
  { double mm = 12.0/20.0; double minl = 720.0*mm; double ss = mm;
    while (minl >= 12.0 && ns < MAXS) { scl[ns++] = ss; ss *= 0.709; minl *= 0.709; } }

  PAll P{}; P.ns = ns;
  int tot_img=0, tot_pool=0, tot_c2=0, tot_n=0, tot_k=0;
  P.blkR[0]=P.blkC1[0]=P.blkC2[0]=P.blkH[0]=0;
  for (int i = 0; i < ns; ++i) {
    SInfo& S = P.s[i];
    S.oh = (int)(720.0*scl[i] + 1.0); S.ow = (int)(1280.0*scl[i] + 1.0);
    int h1 = S.oh-2, w1 = S.ow-2;
    S.hp = (h1+1)/2; S.wp = (w1+1)/2;
    S.h2 = S.hp-2; S.w2 = S.wp-2;
    S.hc = S.hp-4; S.wc = S.wp-4;
    S.n = NB*S.hc*S.wc;
    S.k = S.n < 1024 ? S.n : 1024;
    S.scf = (float)scl[i];
    S.img_off = tot_img;   tot_img  += NB*3*S.oh*S.ow;
    S.pool_off = tot_pool; tot_pool += NB*10*S.hp*S.wp;
    S.c2_off = tot_c2;     tot_c2   += NB*16*S.h2*S.w2;
    S.nk_off = tot_n;      tot_n    += S.n;
    S.cand_base = tot_k;   tot_k    += S.k;
    P.blkR[i+1]  = P.blkR[i]  + (NB*3*S.oh*S.ow + 255)/256;
    P.blkC1[i+1] = P.blkC1[i] + (NB*10*S.hp*S.wp + 255)/256;
    P.blkC2[i+1] = P.blkC2[i] + (NB*16*S.h2*S.w2 + 255)/256;
    P.blkH[i+1]  = P.blkH[i]  + (S.n + 255)/256;
  }

  // fixed per-scale regions in reduce ping-pong buffers (sizes only shrink per stage)
  int regA[MAXS] = {0}, regB[MAXS] = {0};
  long offA = 0, offB = 0;
  for (int i = 0; i < ns; ++i) {
    if (P.s[i].n > 4096) {
      int nb = (P.s[i].n + 4095)/4096;
      regA[i] = (int)offA; offA += (long)nb*1024;
      int n1 = nb*1024;
      if (n1 > 4096) { int nb1 = (n1 + 4095)/4096; regB[i] = (int)offB; offB += (long)nb1*1024; }
    }
  }
  long redAe = offA > 6144 ? offA : 6144;   // also reused for global stage A (3*2048)
  long redBe = offB > 4096 ? offB : 4096;   // also reused for global stage B (2*2048)

  // workspace layout
  char* wsb = (char*)d_ws; size_t wo = 0;
  auto take = [&](size_t bytes)->size_t { size_t r = wo; wo += (bytes + 255) & ~(size_t)255; return r; };
  float*  rsz    = (float*) (wsb + take((size_t)tot_img*4));
  float*  poolb  = (float*) (wsb + take((size_t)tot_pool*4));
  float*  c2buf  = (float*) (wsb + take((size_t)tot_c2*4));
  float4* reg4   = (float4*)(wsb + take((size_t)tot_n*16));
  u64*    keys   = (u64*)   (wsb + take((size_t)tot_n*8));
  u64*    redA   = (u64*)   (wsb + take((size_t)redAe*8));
  u64*    redB   = (u64*)   (wsb + take((size_t)redBe*8));
  float*  cb9    = (float*) (wsb + take((size_t)tot_k*9*4));
  int*    cinds  = (int*)   (wsb + take((size_t)tot_k*4));
  u64*    candk  = (u64*)   (wsb + take((size_t)tot_k*8));
  u64*    gsort  = (u64*)   (wsb + take((size_t)KG*8));
  int*    gkeep  = (int*)   (wsb + take((size_t)KG*4));
  if (wo > ws_size) return;  // insufficient workspace (would need ~118 MB)

  k_resize    <<<P.blkR[ns],  256, 0, stream>>>(imgs, rsz, P);
  k_conv1pool <<<P.blkC1[ns], 256, 0, stream>>>(rsz, c1w, c1b, a1, poolb, P);
  k_conv2     <<<P.blkC2[ns], 256, 0, stream>>>(poolb, c2w, c2b, a2, c2buf, P);
  k_conv3heads<<<P.blkH[ns],  256, 0, stream>>>(c2buf, c3w, c3b, a3, c41w, c41b, c42w, c42b,
                                                keys, reg4, P);

  // per-scale hierarchical top-k
  struct Cur { int buf, off, n; } cur[MAXS];
  for (int i = 0; i < ns; ++i) { cur[i].buf = 0; cur[i].off = P.s[i].nk_off; cur[i].n = P.s[i].n; }
  for (int stage = 0; ; ++stage) {
    RedArgs ra{}; ra.ne = 0; ra.outk = 1024; int tb = 0;
    int ob = (stage & 1) ? 2 : 1;
    for (int i = 0; i < ns; ++i) if (cur[i].n > 4096) {
      int nb = (cur[i].n + 4095)/4096;
      RedEnt& e = ra.e[ra.ne++];
      e.in_buf = cur[i].buf; e.in_off = cur[i].off; e.n = cur[i].n;
      e.blk_start = tb; e.nblk = nb;
      e.out_off = (ob == 1) ? regA[i] : regB[i];
      tb += nb;
      cur[i].buf = ob; cur[i].off = e.out_off; cur[i].n = nb*1024;
    }
    if (!ra.ne) break;
    k_topk_reduce<<<tb, 256, 0, stream>>>(keys, redA, redB, candk,
                                          (ob == 1) ? redA : redB, ra);
  }

  FinArgs fa{};
  for (int i = 0; i < ns; ++i) {
    FinEnt& f = fa.e[i];
    f.in_buf = cur[i].buf; f.in_off = cur[i].off; f.n = cur[i].n;
    f.k = P.s[i].k; f.hc = P.s[i].hc; f.wc = P.s[i].wc;
    f.cand_base = P.s[i].cand_base; f.nk_off = P.s[i].nk_off; f.scf = P.s[i].scf;
  }
  k_final_gather<<<ns, 256, 0, stream>>>(keys, redA, redB, reg4, cb9, cinds, fa);

  NmsArgs na{};
  for (int i = 0; i < ns; ++i) { na.base[i] = P.s[i].cand_base; na.kk[i] = P.s[i].k; }
  k_nms_scale<<<ns, 64, 0, stream>>>(cb9, cinds, candk, na);

  // global top-2048: candk (tot_k=9236) -> redA (3*2048) -> redB (2*2048) -> gsort
  {
    int nb1 = (tot_k + 4095)/4096;                  // 3
    RedArgs ra{}; ra.ne = 1; ra.outk = KG;
    ra.e[0].in_buf = 3; ra.e[0].in_off = 0; ra.e[0].n = tot_k;
    ra.e[0].blk_start = 0; ra.e[0].nblk = nb1; ra.e[0].out_off = 0;
    k_topk_reduce<<<nb1, 256, 0, stream>>>(keys, redA, redB, candk, redA, ra);
    int n2 = nb1*KG;                                // 6144
    int nb2 = (n2 + 4095)/4096;                     // 2
    RedArgs rb{}; rb.ne = 1; rb.outk = KG;
    rb.e[0].in_buf = 1; rb.e[0].in_off = 0; rb.e[0].n = n2;
    rb.e[0].blk_start = 0; rb.e[0].nblk = nb2; rb.e[0].out_off = 0;
    k_topk_reduce<<<nb2, 256, 0, stream>>>(keys, redA, redB, candk, redB, rb);
  }
  k_gfinal    <<<1, 256, 0, stream>>>(redB, gsort);
  k_nms_global<<<1, 64,  0, stream>>>(gsort, cb9, cinds, gkeep);
  k_finalize  <<<(KG + 255)/256, 256, 0, stream>>>(gsort, gkeep, cb9, cinds, out);
}

// Round 2
// 2768.701 us; speedup vs baseline: 1.4276x; 1.4276x over previous
//
#include <hip/hip_runtime.h>
#include <math.h>

typedef unsigned long long u64;

#define MAXS 16
#define NB 4
#define IH 720
#define IW 1280
#define OFFC 5120.0f   // 4.0 * max(h,w)
#define KG 2048

// ---------------- shared host/device structs ----------------
struct SInfo {
  int oh, ow, hp, wp, h2, w2, hc, wc, n, k;
  float scf;
  int img_off, pool_off, c2_off, nk_off, cand_base;
};
struct PAll {
  SInfo s[MAXS];
  int blkR[MAXS+1], blkC1[MAXS+1], blkC2[MAXS+1], blkH[MAXS+1];
  int ns;
};
struct RedEnt { int in_buf, blk_start, nblk, in_off, out_off, n; };
struct RedArgs { RedEnt e[MAXS]; int ne, outk; };
struct FinEnt { int in_buf, in_off, n, k, hc, wc, cand_base, nk_off; float scf; };
struct FinArgs { FinEnt e[MAXS]; };
struct NmsArgs { int base[MAXS], kk[MAXS]; };

// ---------------- key helpers: total order matching lax.top_k ----------------
__device__ __forceinline__ u64 makekey(float v, unsigned idx) {
  unsigned b = __float_as_uint(v);
  unsigned u = (b & 0x80000000u) ? ~b : (b | 0x80000000u);
  return ((u64)u << 32) | (unsigned)(~idx);
}
__device__ __forceinline__ float keyval(u64 c) {
  unsigned u = (unsigned)(c >> 32);
  unsigned b = (u & 0x80000000u) ? (u ^ 0x80000000u) : ~u;
  return __uint_as_float(b);
}

// ---------------- 1a. area resize pass 1: pool rows (coalesced along x) ----------------
// thread -> (bc, y_out, x), x fastest. Wave reads 64 contiguous floats per iter.
__global__ __launch_bounds__(256) void k_rrows(const float* __restrict__ img,
                                               float* __restrict__ rowp, int oh) {
  int idx = blockIdx.x*256 + threadIdx.x;
  int total = NB*3*oh*IW;
  if (idx >= total) return;
  int x = idx % IW; int t = idx / IW;
  int y = t % oh; int bc = t / oh;
  int hs = (y*IH)/oh, he = ((y+1)*IH + oh - 1)/oh;
  float rh = 1.0f/(float)(he-hs);
  const float* bp = img + (size_t)bc*IH*IW + x;
  float cs = 0.f;
  for (int yy = hs; yy < he; ++yy) cs += bp[(size_t)yy*IW] * rh;  // same order as fused version
  rowp[idx] = cs;
}

// ---------------- 1b. area resize pass 2: pool cols + normalize ----------------
__global__ __launch_bounds__(256) void k_rcols(const float* __restrict__ rowp,
                                               float* __restrict__ out, int ow, int img_off) {
  int idx = blockIdx.x*256 + threadIdx.x;
  // total = NB*3*oh*ow passed implicitly via grid; guard with ow-derived bound:
  // caller sizes grid to ceil(NB*3*oh*ow/256); we re-derive row index.
  int xo = idx % ow; int row = idx / ow;      // row = bc*oh + y
  float rw;
  int ws_ = (xo*IW)/ow, we_ = ((xo+1)*IW + ow - 1)/ow;
  rw = 1.0f/(float)(we_-ws_);
  const float* rp = rowp + (size_t)row*IW;
  float acc = 0.f;
  for (int xx = ws_; xx < we_; ++xx) acc += rp[xx] * rw;          // same order as fused version
  out[img_off + idx] = (acc - 127.5f) * 0.0078125f;
}

// ---------------- 2. conv1(3x3,10ch) + PReLU + ceil-maxpool2 (fused) ----------------
__global__ __launch_bounds__(256) void k_conv1pool(const float* __restrict__ rsz,
    const float* __restrict__ w1, const float* __restrict__ b1, const float* __restrict__ a1,
    float* __restrict__ pool, PAll P) {
  int blk = blockIdx.x, si = 0;
  while (si + 1 < P.ns && blk >= P.blkC1[si+1]) ++si;
  SInfo S = P.s[si];
  int local = (blk - P.blkC1[si]) * 256 + threadIdx.x;
  int total = NB*10*S.hp*S.wp;
  if (local >= total) return;
  int x = local % S.wp; int t = local / S.wp;
  int y = t % S.hp; t /= S.hp;
  int o = t % 10; int b = t / 10;
  int H1 = S.oh - 2, W1 = S.ow - 2;
  float m = -INFINITY;
  for (int dy = 0; dy < 2; ++dy) {
    int ry = 2*y + dy; if (ry >= H1) continue;
    for (int dx = 0; dx < 2; ++dx) {
      int rx = 2*x + dx; if (rx >= W1) continue;
      float v = 0.f;
      for (int c = 0; c < 3; ++c) {
        const float* ip = rsz + S.img_off + ((b*3 + c)*S.oh + ry)*S.ow + rx;
        #pragma unroll
        for (int ky = 0; ky < 3; ++ky)
          #pragma unroll
          for (int kx = 0; kx < 3; ++kx)
            v += ip[ky*S.ow + kx] * w1[((o*3 + c)*3 + ky)*3 + kx];
      }
      v += b1[o];
      v = v > 0.f ? v : a1[o]*v;
      m = fmaxf(m, v);
    }
  }
  pool[S.pool_off + local] = m;
}

// ---------------- 3. conv2(3x3,16ch) + PReLU ----------------
__global__ __launch_bounds__(256) void k_conv2(const float* __restrict__ pool,
    const float* __restrict__ w2, const float* __restrict__ b2w, const float* __restrict__ a2,
    float* __restrict__ c2o, PAll P) {
  int blk = blockIdx.x, si = 0;
  while (si + 1 < P.ns && blk >= P.blkC2[si+1]) ++si;
  SInfo S = P.s[si];
  int local = (blk - P.blkC2[si]) * 256 + threadIdx.x;
  int total = NB*16*S.h2*S.w2;
  if (local >= total) return;
  int x = local % S.w2; int t = local / S.w2;
  int y = t % S.h2; t /= S.h2;
  int o = t % 16; int b = t / 16;
  float v = 0.f;
  for (int c = 0; c < 10; ++c) {
    const float* ip = pool + S.pool_off + ((b*10 + c)*S.hp + y)*S.wp + x;
    #pragma unroll
    for (int ky = 0; ky < 3; ++ky)
      #pragma unroll
      for (int kx = 0; kx < 3; ++kx)
        v += ip[ky*S.wp + kx] * w2[((o*10 + c)*3 + ky)*3 + kx];
  }
  v += b2w[o];
  v = v > 0.f ? v : a2[o]*v;
  c2o[S.c2_off + local] = v;
}

// ---------------- 4. conv3(3x3,32ch)+PReLU + 1x1 heads + softmax + key/reg emit ----------------
__global__ __launch_bounds__(256) void k_conv3heads(const float* __restrict__ c2,
    const float* __restrict__ w3, const float* __restrict__ b3, const float* __restrict__ a3,
    const float* __restrict__ w41, const float* __restrict__ b41,
    const float* __restrict__ w42, const float* __restrict__ b42,
    u64* __restrict__ keys, float4* __restrict__ reg4, PAll P) {
  int blk = blockIdx.x, si = 0;
  while (si + 1 < P.ns && blk >= P.blkH[si+1]) ++si;
  SInfo S = P.s[si];
  int local = (blk - P.blkH[si]) * 256 + threadIdx.x;
  if (local >= S.n) return;
  int x = local % S.wc; int t = local / S.wc;
  int y = t % S.hc; int b = t / S.hc;
  float acc[32];
  #pragma unroll
  for (int oc = 0; oc < 32; ++oc) acc[oc] = 0.f;
  int chs = S.h2 * S.w2;
  for (int ky = 0; ky < 3; ++ky)
    for (int kx = 0; kx < 3; ++kx) {
      const float* ip = c2 + S.c2_off + ((b*16)*S.h2 + (y+ky))*S.w2 + (x+kx);
      float v[16];
      #pragma unroll
      for (int ic = 0; ic < 16; ++ic) v[ic] = ip[ic*chs];
      #pragma unroll
      for (int oc = 0; oc < 32; ++oc) {
        float tt = 0.f;
        #pragma unroll
        for (int ic = 0; ic < 16; ++ic)
          tt += v[ic] * w3[((oc*16 + ic)*3 + ky)*3 + kx];
        acc[oc] += tt;
      }
    }
  float l0 = 0.f, l1 = 0.f, r0 = 0.f, r1 = 0.f, r2 = 0.f, r3 = 0.f;
  #pragma unroll
  for (int oc = 0; oc < 32; ++oc) {
    float vv = acc[oc] + b3[oc];
    vv = vv > 0.f ? vv : a3[oc]*vv;
    l0 += vv * w41[oc];      l1 += vv * w41[32 + oc];
    r0 += vv * w42[oc];      r1 += vv * w42[32 + oc];
    r2 += vv * w42[64 + oc]; r3 += vv * w42[96 + oc];
  }
  l0 += b41[0]; l1 += b41[1];
  r0 += b42[0]; r1 += b42[1]; r2 += b42[2]; r3 += b42[3];
  float mx = fmaxf(l0, l1);
  float e0 = expf(l0 - mx), e1 = expf(l1 - mx);
  float score = e1 / (e0 + e1);
  float kv = (score >= 0.6f) ? score : -INFINITY;
  keys[S.nk_off + local] = makekey(kv, (unsigned)local);
  reg4[S.nk_off + local] = make_float4(r0, r1, r2, r3);
}

// ---------------- bitonic sort (4096, descending) in LDS ----------------
__device__ inline void bitonic4096_desc(u64* sh) {
  for (int kk = 2; kk <= 4096; kk <<= 1)
    for (int j = kk >> 1; j > 0; j >>= 1) {
      __syncthreads();
      for (int i = threadIdx.x; i < 4096; i += 256) {
        int ixj = i ^ j;
        if (ixj > i) {
          u64 a = sh[i], b = sh[ixj];
          if (((i & kk) == 0) ? (a < b) : (a > b)) { sh[i] = b; sh[ixj] = a; }
        }
      }
    }
  __syncthreads();
}

// ---------------- 5. hierarchical top-k reduce ----------------
__global__ __launch_bounds__(256) void k_topk_reduce(const u64* __restrict__ b0,
    const u64* __restrict__ b1, const u64* __restrict__ b2, const u64* __restrict__ b3,
    u64* __restrict__ outb, RedArgs ra) {
  __shared__ u64 sh[4096];
  int blk = blockIdx.x, ei = 0;
  while (ei + 1 < ra.ne && blk >= ra.e[ei].blk_start + ra.e[ei].nblk) ++ei;
  RedEnt e = ra.e[ei];
  int chunk = blk - e.blk_start;
  const u64* in = (e.in_buf == 0 ? b0 : e.in_buf == 1 ? b1 : e.in_buf == 2 ? b2 : b3)
                  + e.in_off + (size_t)chunk*4096;
  int m = e.n - chunk*4096; if (m > 4096) m = 4096;
  for (int i = threadIdx.x; i < 4096; i += 256) sh[i] = (i < m) ? in[i] : 0ULL;
  bitonic4096_desc(sh);
  u64* o = outb + e.out_off + (size_t)chunk * ra.outk;
  for (int i = threadIdx.x; i < ra.outk; i += 256) o[i] = sh[i];
}

// ---------------- 6. final per-scale sort + candidate gather ----------------
__global__ __launch_bounds__(256) void k_final_gather(const u64* __restrict__ b0,
    const u64* __restrict__ b1, const u64* __restrict__ b2,
    const float4* __restrict__ reg4, float* __restrict__ cb9, int* __restrict__ cinds,
    FinArgs fa) {
  __shared__ u64 sh[4096];
  FinEnt f = fa.e[blockIdx.x];
  const u64* in = (f.in_buf == 0 ? b0 : f.in_buf == 1 ? b1 : b2) + f.in_off;
  for (int i = threadIdx.x; i < 4096; i += 256) sh[i] = (i < f.n) ? in[i] : 0ULL;
  bitonic4096_desc(sh);
  for (int i = threadIdx.x; i < f.k; i += 256) {
    u64 c = sh[i];
    float val = keyval(c);
    unsigned idx = ~(unsigned)c;
    int x = (int)(idx % (unsigned)f.wc); unsigned t2 = idx / (unsigned)f.wc;
    int y = (int)(t2 % (unsigned)f.hc); int b = (int)(t2 / (unsigned)f.hc);
    float cx = (float)x, cy = (float)y;
    float x1 = floorf((2.0f*cx + 1.0f)/f.scf);
    float y1 = floorf((2.0f*cy + 1.0f)/f.scf);
    float x2 = floorf((2.0f*cx + 12.0f)/f.scf);
    float y2 = floorf((2.0f*cy + 12.0f)/f.scf);
    float4 rg = reg4[f.nk_off + idx];
    int g = f.cand_base + i;
    float* p = cb9 + (size_t)g*9;
    p[0]=x1; p[1]=y1; p[2]=x2; p[3]=y2; p[4]=val;
    p[5]=rg.x; p[6]=rg.y; p[7]=rg.z; p[8]=rg.w;
    cinds[g] = b;
  }
}

// ---------------- 7. per-scale greedy NMS (1 wave / scale), writes global keys ----------------
__global__ __launch_bounds__(64) void k_nms_scale(const float* __restrict__ cb9,
    const int* __restrict__ cinds, u64* __restrict__ candk, NmsArgs na) {
  __shared__ float sx1[1024], sy1[1024], sx2[1024], sy2[1024], sar[1024], ssc[1024];
  int s = blockIdx.x, base = na.base[s], k = na.kk[s];
  int lane = threadIdx.x;
  for (int j = lane; j < k; j += 64) {
    const float* p = cb9 + (size_t)(base + j)*9;
    float off = OFFC * (float)cinds[base + j];
    float a = p[0] + off, b = p[1] + off, c = p[2] + off, d = p[3] + off;
    sx1[j]=a; sy1[j]=b; sx2[j]=c; sy2[j]=d;
    sar[j] = (c - a + 1.0f) * (d - b + 1.0f);
    ssc[j] = p[4];
  }
  __syncthreads();
  unsigned sup = 0, kept = 0;
  for (int i = 0; i < k; ++i) {
    int owner = i & 63, bit = i >> 6;
    unsigned so = (unsigned)__shfl((int)sup, owner);
    bool keep_i = (ssc[i] != -INFINITY) && !((so >> bit) & 1u);
    if (keep_i) {
      if (lane == owner) kept |= 1u << bit;
      float xi1 = sx1[i], yi1 = sy1[i], xi2 = sx2[i], yi2 = sy2[i], ai = sar[i];
      #pragma unroll
      for (int t = 0; t < 16; ++t) {
        int j = t*64 + lane;
        if (j > i && j < k) {
          float iw = fminf(xi2, sx2[j]) - fmaxf(xi1, sx1[j]) + 1.0f; iw = fmaxf(iw, 0.0f);
          float ih = fminf(yi2, sy2[j]) - fmaxf(yi1, sy1[j]) + 1.0f; ih = fmaxf(ih, 0.0f);
          float inter = iw*ih;
          if (inter / (ai + sar[j] - inter) > 0.5f) sup |= 1u << t;
        }
      }
    }
  }
  for (int t = 0; t < 16; ++t) {
    int j = t*64 + lane;
    if (j < k) {
      float v = ((kept >> t) & 1u) ? ssc[j] : -INFINITY;
      candk[base + j] = makekey(v, (unsigned)(base + j));
    }
  }
}

// ---------------- 8. global final sort (4096 -> top 2048) ----------------
__global__ __launch_bounds__(256) void k_gfinal(const u64* __restrict__ in, u64* __restrict__ gs) {
  __shared__ u64 sh[4096];
  for (int i = threadIdx.x; i < 4096; i += 256) sh[i] = in[i];
  bitonic4096_desc(sh);
  for (int i = threadIdx.x; i < KG; i += 256) gs[i] = sh[i];
}

// ---------------- 9. global greedy NMS (thresh 0.7) ----------------
__global__ __launch_bounds__(64) void k_nms_global(const u64* __restrict__ gs,
    const float* __restrict__ cb9, const int* __restrict__ cinds, int* __restrict__ gkeep) {
  __shared__ float sx1[KG], sy1[KG], sx2[KG], sy2[KG], sar[KG], ssc[KG];
  int lane = threadIdx.x;
  for (int j = lane; j < KG; j += 64) {
    u64 c = gs[j];
    unsigned g = ~(unsigned)c;
    const float* p = cb9 + (size_t)g*9;
    float off = OFFC * (float)cinds[g];
    float a = p[0] + off, b = p[1] + off, cc = p[2] + off, d = p[3] + off;
    sx1[j]=a; sy1[j]=b; sx2[j]=cc; sy2[j]=d;
    sar[j] = (cc - a + 1.0f) * (d - b + 1.0f);
    ssc[j] = keyval(c);
  }
  __syncthreads();
  unsigned sup = 0, kept = 0;
  for (int i = 0; i < KG; ++i) {
    int owner = i & 63, bit = i >> 6;
    unsigned so = (unsigned)__shfl((int)sup, owner);
    bool keep_i = (ssc[i] != -INFINITY) && !((so >> bit) & 1u);
    if (keep_i) {
      if (lane == owner) kept |= 1u << bit;
      float xi1 = sx1[i], yi1 = sy1[i], xi2 = sx2[i], yi2 = sy2[i], ai = sar[i];
      #pragma unroll
      for (int t = 0; t < 32; ++t) {
        int j = t*64 + lane;
        if (j > i) {
          float iw = fminf(xi2, sx2[j]) - fmaxf(xi1, sx1[j]) + 1.0f; iw = fmaxf(iw, 0.0f);
          float ih = fminf(yi2, sy2[j]) - fmaxf(yi1, sy1[j]) + 1.0f; ih = fmaxf(ih, 0.0f);
          float inter = iw*ih;
          if (inter / (ai + sar[j] - inter) > 0.7f) sup |= 1u << t;
        }
      }
    }
  }
  for (int t = 0; t < 32; ++t) { int j = t*64 + lane; gkeep[j] = (int)((kept >> t) & 1u); }
}

// ---------------- 10. refinement + output ----------------
__global__ __launch_bounds__(256) void k_finalize(const u64* __restrict__ gs,
    const int* __restrict__ gkeep, const float* __restrict__ cb9, const int* __restrict__ cinds,
    float* __restrict__ out) {
  int r = blockIdx.x*256 + threadIdx.x;
  if (r >= KG) return;
  u64 c = gs[r];
  unsigned g = ~(unsigned)c;
  float val = keyval(c);
  const float* p = cb9 + (size_t)g*9;
  int ind = cinds[g];
  bool valid = (val != -INFINITY) && (gkeep[r] != 0);
  float b0=p[0], b1v=p[1], b2v=p[2], b3=p[3], sc=p[4], r5=p[5], r6=p[6], r7=p[7], r8=p[8];
  float regw = b2v - b0, regh = b3 - b1v;
  float qq1 = b0 + r5*regw, qq2 = b1v + r6*regh, qq3 = b2v + r7*regw, qq4 = b3 + r8*regh;
  float bw = qq3 - qq1, bh = qq4 - qq2;
  float l = fmaxf(bw, bh);
  float x1n = qq1 + bw*0.5f - l*0.5f;
  float y1n = qq2 + bh*0.5f - l*0.5f;
  float o0 = x1n, o1 = y1n, o2 = x1n + l, o3 = y1n + l, o4 = sc;
  if (!valid) { o0=o1=o2=o3=o4=0.f; }
  out[r*5+0]=o0; out[r*5+1]=o1; out[r*5+2]=o2; out[r*5+3]=o3; out[r*5+4]=o4;
  out[5*KG + r] = valid ? 1.0f : 0.0f;
  out[6*KG + r] = (float)ind;
}

// ---------------- host ----------------
extern "C" void kernel_launch(void* const* d_in, const int* in_sizes, int n_in,
                              void* d_out, int out_size, void* d_ws, size_t ws_size,
                              hipStream_t stream) {
  (void)in_sizes; (void)n_in; (void)out_size;
  const float* imgs = (const float*)d_in[0];
  const float* c1w  = (const float*)d_in[1];
  const float* c1b  = (const float*)d_in[2];
  const float* a1   = (const float*)d_in[3];
  const float* c2w  = (const float*)d_in[4];
  const float* c2b  = (const float*)d_in[5];
  const float* a2   = (const float*)d_in[6];
  const float* c3w  = (const float*)d_in[7];
  const float* c3b  = (const float*)d_in[8];
  const float* a3   = (const float*)d_in[9];
  const float* c41w = (const float*)d_in[10];
  const float* c41b = (const float*)d_in[11];
  const float* c42w = (const float*)d_in[12];
  const float* c42b = (const float*)d_in[13];
  float* out = (float*)d_out;

  // scale pyramid, exactly mirroring the Python double-precision loop
  int ns = 0; double scl[MAXS];
  { double mm = 12.0/20.0; double minl = 720.0*mm; double ss = mm;
    while (minl >= 12.0 && ns < MAXS) { scl[ns++] = ss; ss *= 0.709; minl *= 0.709; } }

  PAll P{}; P.ns = ns;
  int tot_img=0, tot_pool=0, tot_c2=0, tot_n=0, tot_k=0;
  P.blkR[0]=P.blkC1[0]=P.blkC2[0]=P.blkH[0]=0;
  for (int i = 0; i < ns; ++i) {
    SInfo& S = P.s[i];
    S.oh = (int)(720.0*scl[i] + 1.0); S.ow = (int)(1280.0*scl[i] + 1.0);
    int h1 = S.oh-2, w1 = S.ow-2;
    S.hp = (h1+1)/2; S.wp = (w1+1)/2;
    S.h2 = S.hp-2; S.w2 = S.wp-2;
    S.hc = S.hp-4; S.wc = S.wp-4;
    S.n = NB*S.hc*S.wc;
    S.k = S.n < 1024 ? S.n : 1024;
    S.scf = (float)scl[i];
    S.img_off = tot_img;   tot_img  += NB*3*S.oh*S.ow;
    S.pool_off = tot_pool; tot_pool += NB*10*S.hp*S.wp;
    S.c2_off = tot_c2;     tot_c2   += NB*16*S.h2*S.w2;
    S.nk_off = tot_n;      tot_n    += S.n;
    S.cand_base = tot_k;   tot_k    += S.k;
    P.blkR[i+1]  = P.blkR[i]  + (NB*3*S.oh*S.ow + 255)/256;
    P.blkC1[i+1] = P.blkC1[i] + (NB*10*S.hp*S.wp + 255)/256;
    P.blkC2[i+1] = P.blkC2[i] + (NB*16*S.h2*S.w2 + 255)/256;
    P.blkH[i+1]  = P.blkH[i]  + (S.n + 255)/256;
  }

  // fixed per-scale regions in reduce ping-pong buffers (sizes only shrink per stage)
  int regA[MAXS] = {0}, regB[MAXS] = {0};
  long offA = 0, offB = 0;
  for (int i = 0; i < ns; ++i) {
    if (P.s[i].n > 4096) {
      int nb = (P.s[i].n + 4095)/4096;
      regA[i] = (int)offA; offA += (long)nb*1024;
      int n1 = nb*1024;
      if (n1 > 4096) { int nb1 = (n1 + 4095)/4096; regB[i] = (int)offB; offB += (long)nb1*1024; }
    }
  }
  long redAe = offA > 6144 ? offA : 6144;
  long redBe = offB > 4096 ? offB : 4096;

  // workspace layout
  char* wsb = (char*)d_ws; size_t wo = 0;
  auto take = [&](size_t bytes)->size_t { size_t r = wo; wo += (bytes + 255) & ~(size_t)255; return r; };
  float*  rsz    = (float*) (wsb + take((size_t)tot_img*4));
  float*  poolb  = (float*) (wsb + take((size_t)tot_pool*4));
  size_t  c2_off_b = take((size_t)tot_c2*4);
  float*  c2buf  = (float*) (wsb + c2_off_b);
  float4* reg4   = (float4*)(wsb + take((size_t)tot_n*16));
  u64*    keys   = (u64*)   (wsb + take((size_t)tot_n*8));
  u64*    redA   = (u64*)   (wsb + take((size_t)redAe*8));
  u64*    redB   = (u64*)   (wsb + take((size_t)redBe*8));
  float*  cb9    = (float*) (wsb + take((size_t)tot_k*9*4));
  int*    cinds  = (int*)   (wsb + take((size_t)tot_k*4));
  u64*    candk  = (u64*)   (wsb + take((size_t)tot_k*8));
  u64*    gsort  = (u64*)   (wsb + take((size_t)KG*8));
  int*    gkeep  = (int*)   (wsb + take((size_t)KG*4));

  // row-pool intermediate: aliases c2buf (written only later, at k_conv2 stage).
  // Needs NB*3*max_oh*IW floats; falls back to a fresh region if it doesn't fit.
  size_t rowp_need = (size_t)NB*3*P.s[0].oh*IW*4;
  float* rowp = ((size_t)tot_c2*4 >= rowp_need) ? c2buf
              : (float*)(wsb + take(rowp_need));
  if (wo > ws_size) return;  // insufficient workspace

  // --- resize: two-pass separable (per scale, reusing rowp) ---
  for (int i = 0; i < ns; ++i) {
    const SInfo& S = P.s[i];
    int t1 = NB*3*S.oh*IW;
    int t2 = NB*3*S.oh*S.ow;
    k_rrows<<<(t1 + 255)/256, 256, 0, stream>>>(imgs, rowp, S.oh);
    k_rcols<<<(t2 + 255)/256, 256, 0, stream>>>(rowp, rsz, S.ow, S.img_off);
  }

  k_conv1pool <<<P.blkC1[ns], 256, 0, stream>>>(rsz, c1w, c1b, a1, poolb, P);
  k_conv2     <<<P.blkC2[ns], 256, 0, stream>>>(poolb, c2w, c2b, a2, c2buf, P);
  k_conv3heads<<<P.blkH[ns],  256, 0, stream>>>(c2buf, c3w, c3b, a3, c41w, c41b, c42w, c42b,
                                                keys, reg4, P);

  // per-scale hierarchical top-k
  struct Cur { int buf, off, n; } cur[MAXS];
  for (int i = 0; i < ns; ++i) { cur[i].buf = 0; cur[i].off = P.s[i].nk_off; cur[i].n = P.s[i].n; }
  for (int stage = 0; ; ++stage) {
    RedArgs ra{}; ra.ne = 0; ra.outk = 1024; int tb = 0;
    int ob = (stage & 1) ? 2 : 1;
    for (int i = 0; i < ns; ++i) if (cur[i].n > 4096) {
      int nb = (cur[i].n + 4095)/4096;
      RedEnt& e = ra.e[ra.ne++];
      e.in_buf = cur[i].buf; e.in_off = cur[i].off; e.n = cur[i].n;
      e.blk_start = tb; e.nblk = nb;
      e.out_off = (ob == 1) ? regA[i] : regB[i];
      tb += nb;
      cur[i].buf = ob; cur[i].off = e.out_off; cur[i].n = nb*1024;
    }
    if (!ra.ne) break;
    k_topk_reduce<<<tb, 256, 0, stream>>>(keys, redA, redB, candk,
                                          (ob == 1) ? redA : redB, ra);
  }

  FinArgs fa{};
  for (int i = 0; i < ns; ++i) {
    FinEnt& f = fa.e[i];
    f.in_buf = cur[i].buf; f.in_off = cur[i].off; f.n = cur[i].n;
    f.k = P.s[i].k; f.hc = P.s[i].hc; f.wc = P.s[i].wc;
    f.cand_base = P.s[i].cand_base; f.nk_off = P.s[i].nk_off; f.scf = P.s[i].scf;
  }
  k_final_gather<<<ns, 256, 0, stream>>>(keys, redA, redB, reg4, cb9, cinds, fa);

  NmsArgs na{};
  for (int i = 0; i < ns; ++i) { na.base[i] = P.s[i].cand_base; na.kk[i] = P.s[i].k; }
  k_nms_scale<<<ns, 64, 0, stream>>>(cb9, cinds, candk, na);

  // global top-2048: candk -> redA -> redB -> gsort
  {
    int nb1 = (tot_k + 4095)/4096;
    RedArgs ra{}; ra.ne = 1; ra.outk = KG;
    ra.e[0].in_buf = 3; ra.e[0].in_off = 0; ra.e[0].n = tot_k;
    ra.e[0].blk_start = 0; ra.e[0].nblk = nb1; ra.e[0].out_off = 0;
    k_topk_reduce<<<nb1, 256, 0, stream>>>(keys, redA, redB, candk, redA, ra);
    int n2 = nb1*KG;
    int nb2 = (n2 + 4095)/4096;
    RedArgs rb{}; rb.ne = 1; rb.outk = KG;
    rb.e[0].in_buf = 1; rb.e[0].in_off = 0; rb.e[0].n = n2;
    rb.e[0].blk_start = 0; rb.e[0].nblk = nb2; rb.e[0].out_off = 0;
    k_topk_reduce<<<nb2, 256, 0, stream>>>(keys, redA, redB, candk, redB, rb);
  }
  k_gfinal    <<<1, 256, 0, stream>>>(redB, gsort);
  k_nms_global<<<1, 64,  0, stream>>>(gsort, cb9, cinds, gkeep);
  k_finalize  <<<(KG + 255)/256, 256, 0, stream>>>(gsort, gkeep, cb9, cinds, out);
}

// Round 3
// 2444.999 us; speedup vs baseline: 1.6166x; 1.1324x over previous
//
#include <hip/hip_runtime.h>
#include <math.h>

typedef unsigned long long u64;

#define MAXS 16
#define NB 4
#define IH 720
#define IW 1280
#define OFFC 5120.0f   // 4.0 * max(h,w)
#define KG 2048

// ---------------- shared host/device structs ----------------
struct SInfo {
  int oh, ow, hp, wp, h2, w2, hc, wc, n, k;
  float scf;
  int img_off, pool_off, c2_off, nk_off, cand_base;
  int g1x, g1y, g2x, g2y, g3x, g3y;   // tiled grid dims per conv stage
};
struct PAll {
  SInfo s[MAXS];
  int blkC1[MAXS+1], blkC2[MAXS+1], blkH[MAXS+1];
  int ns;
};
struct RedEnt { int in_buf, blk_start, nblk, in_off, out_off, n; };
struct RedArgs { RedEnt e[MAXS]; int ne, outk; };
struct FinEnt { int in_buf, in_off, n, k, hc, wc, cand_base, nk_off; float scf; };
struct FinArgs { FinEnt e[MAXS]; };
struct NmsArgs { int base[MAXS], kk[MAXS]; };

// ---------------- key helpers: total order matching lax.top_k ----------------
__device__ __forceinline__ u64 makekey(float v, unsigned idx) {
  unsigned b = __float_as_uint(v);
  unsigned u = (b & 0x80000000u) ? ~b : (b | 0x80000000u);
  return ((u64)u << 32) | (unsigned)(~idx);
}
__device__ __forceinline__ float keyval(u64 c) {
  unsigned u = (unsigned)(c >> 32);
  unsigned b = (u & 0x80000000u) ? (u ^ 0x80000000u) : ~u;
  return __uint_as_float(b);
}

// ---------------- 1a. area resize pass 1: pool rows (coalesced along x) ----------------
__global__ __launch_bounds__(256) void k_rrows(const float* __restrict__ img,
                                               float* __restrict__ rowp, int oh) {
  int idx = blockIdx.x*256 + threadIdx.x;
  int total = NB*3*oh*IW;
  if (idx >= total) return;
  int x = idx % IW; int t = idx / IW;
  int y = t % oh; int bc = t / oh;
  int hs = (y*IH)/oh, he = ((y+1)*IH + oh - 1)/oh;
  float rh = 1.0f/(float)(he-hs);
  const float* bp = img + (size_t)bc*IH*IW + x;
  float cs = 0.f;
  for (int yy = hs; yy < he; ++yy) cs += bp[(size_t)yy*IW] * rh;
  rowp[idx] = cs;
}

// ---------------- 1b. area resize pass 2: pool cols + normalize ----------------
__global__ __launch_bounds__(256) void k_rcols(const float* __restrict__ rowp,
                                               float* __restrict__ out, int ow, int img_off,
                                               int total) {
  int idx = blockIdx.x*256 + threadIdx.x;
  if (idx >= total) return;
  int xo = idx % ow; int row = idx / ow;      // row = bc*oh + y
  int ws_ = (xo*IW)/ow, we_ = ((xo+1)*IW + ow - 1)/ow;
  float rw = 1.0f/(float)(we_-ws_);
  const float* rp = rowp + (size_t)row*IW;
  float acc = 0.f;
  for (int xx = ws_; xx < we_; ++xx) acc += rp[xx] * rw;
  out[img_off + idx] = (acc - 127.5f) * 0.0078125f;
}

// ---------------- 2. conv1(3x3,10ch)+PReLU+ceil-maxpool2, LDS-tiled ----------------
// block = 4 pooled rows x 64 pooled cols for one (scale, image); thread does all 10 oc.
__global__ __launch_bounds__(256) void k_conv1pool_t(const float* __restrict__ rsz,
    const float* __restrict__ w1, const float* __restrict__ b1, const float* __restrict__ a1,
    float* __restrict__ pool, PAll P) {
  __shared__ float sh[3*10*130];    // [c][row 0..9][col 0..129]
  int blk = blockIdx.x, si = 0;
  while (si + 1 < P.ns && blk >= P.blkC1[si+1]) ++si;
  SInfo S = P.s[si];
  int rem = blk - P.blkC1[si];
  int tiles = S.g1x * S.g1y;
  int b = rem / tiles; int r2 = rem % tiles;
  int ty0 = (r2 / S.g1x) * 4, tx0 = (r2 % S.g1x) * 64;
  int tx = threadIdx.x & 63, ty = threadIdx.x >> 6;

  // stage input: rows 2*ty0 .. 2*ty0+9, cols 2*tx0 .. 2*tx0+129, 3 channels
  for (int idx = threadIdx.x; idx < 3*10*130; idx += 256) {
    int cc = idx % 130; int t = idx / 130;
    int rr = t % 10; int c = t / 10;
    int gr = 2*ty0 + rr, gc = 2*tx0 + cc;
    float v = 0.f;
    if (gr < S.oh && gc < S.ow)
      v = rsz[S.img_off + ((b*3 + c)*S.oh + gr)*S.ow + gc];
    sh[(c*10 + rr)*130 + cc] = v;
  }
  __syncthreads();

  int x = tx0 + tx, y = ty0 + ty;
  if (x >= S.wp || y >= S.hp) return;
  int H1 = S.oh - 2, W1 = S.ow - 2;
  float m[10];
  #pragma unroll
  for (int o = 0; o < 10; ++o) m[o] = -INFINITY;
  for (int dy = 0; dy < 2; ++dy) {
    int ry = 2*y + dy; if (ry >= H1) continue;
    int lr = 2*ty + dy;
    for (int dx = 0; dx < 2; ++dx) {
      int rx = 2*x + dx; if (rx >= W1) continue;
      int lc = 2*tx + dx;
      float v[10];
      #pragma unroll
      for (int o = 0; o < 10; ++o) v[o] = 0.f;
      for (int c = 0; c < 3; ++c)
        #pragma unroll
        for (int ky = 0; ky < 3; ++ky)
          #pragma unroll
          for (int kx = 0; kx < 3; ++kx) {
            float s = sh[(c*10 + lr + ky)*130 + lc + kx];
            #pragma unroll
            for (int o = 0; o < 10; ++o)
              v[o] += s * w1[((o*3 + c)*3 + ky)*3 + kx];
          }
      #pragma unroll
      for (int o = 0; o < 10; ++o) {
        float vv = v[o] + b1[o];
        vv = vv > 0.f ? vv : a1[o]*vv;
        m[o] = fmaxf(m[o], vv);
      }
    }
  }
  #pragma unroll
  for (int o = 0; o < 10; ++o)
    pool[S.pool_off + ((b*10 + o)*S.hp + y)*S.wp + x] = m[o];
}

// ---------------- 3. conv2(3x3,10->16)+PReLU, LDS-tiled ----------------
__global__ __launch_bounds__(256) void k_conv2_t(const float* __restrict__ pool,
    const float* __restrict__ w2, const float* __restrict__ b2w, const float* __restrict__ a2,
    float* __restrict__ c2o, PAll P) {
  __shared__ float sh[10*6*66];    // [c][row 0..5][col 0..65]
  int blk = blockIdx.x, si = 0;
  while (si + 1 < P.ns && blk >= P.blkC2[si+1]) ++si;
  SInfo S = P.s[si];
  int rem = blk - P.blkC2[si];
  int tiles = S.g2x * S.g2y;
  int b = rem / tiles; int r2 = rem % tiles;
  int ty0 = (r2 / S.g2x) * 4, tx0 = (r2 % S.g2x) * 64;
  int tx = threadIdx.x & 63, ty = threadIdx.x >> 6;

  for (int idx = threadIdx.x; idx < 10*6*66; idx += 256) {
    int cc = idx % 66; int t = idx / 66;
    int rr = t % 6; int c = t / 6;
    int gr = ty0 + rr, gc = tx0 + cc;
    float v = 0.f;
    if (gr < S.hp && gc < S.wp)
      v = pool[S.pool_off + ((b*10 + c)*S.hp + gr)*S.wp + gc];
    sh[(c*6 + rr)*66 + cc] = v;
  }
  __syncthreads();

  int x = tx0 + tx, y = ty0 + ty;
  if (x >= S.w2 || y >= S.h2) return;
  float acc[16];
  #pragma unroll
  for (int o = 0; o < 16; ++o) acc[o] = 0.f;
  for (int c = 0; c < 10; ++c)
    #pragma unroll
    for (int ky = 0; ky < 3; ++ky)
      #pragma unroll
      for (int kx = 0; kx < 3; ++kx) {
        float s = sh[(c*6 + ty + ky)*66 + tx + kx];
        #pragma unroll
        for (int o = 0; o < 16; ++o)
          acc[o] += s * w2[((o*10 + c)*3 + ky)*3 + kx];
      }
  #pragma unroll
  for (int o = 0; o < 16; ++o) {
    float v = acc[o] + b2w[o];
    v = v > 0.f ? v : a2[o]*v;
    c2o[S.c2_off + ((b*16 + o)*S.h2 + y)*S.w2 + x] = v;
  }
}

// ---------------- 4. conv3(3x3,16->32)+PReLU + heads + softmax, LDS-tiled ----------------
__global__ __launch_bounds__(256) void k_conv3heads_t(const float* __restrict__ c2,
    const float* __restrict__ w3, const float* __restrict__ b3, const float* __restrict__ a3,
    const float* __restrict__ w41, const float* __restrict__ b41,
    const float* __restrict__ w42, const float* __restrict__ b42,
    u64* __restrict__ keys, float4* __restrict__ reg4, PAll P) {
  __shared__ float sh[16*6*66];    // [c][row 0..5][col 0..65] = 25.3 KB
  int blk = blockIdx.x, si = 0;
  while (si + 1 < P.ns && blk >= P.blkH[si+1]) ++si;
  SInfo S = P.s[si];
  int rem = blk - P.blkH[si];
  int tiles = S.g3x * S.g3y;
  int b = rem / tiles; int r2 = rem % tiles;
  int ty0 = (r2 / S.g3x) * 4, tx0 = (r2 % S.g3x) * 64;
  int tx = threadIdx.x & 63, ty = threadIdx.x >> 6;

  for (int idx = threadIdx.x; idx < 16*6*66; idx += 256) {
    int cc = idx % 66; int t = idx / 66;
    int rr = t % 6; int c = t / 6;
    int gr = ty0 + rr, gc = tx0 + cc;
    float v = 0.f;
    if (gr < S.h2 && gc < S.w2)
      v = c2[S.c2_off + ((b*16 + c)*S.h2 + gr)*S.w2 + gc];
    sh[(c*6 + rr)*66 + cc] = v;
  }
  __syncthreads();

  int x = tx0 + tx, y = ty0 + ty;
  if (x >= S.wc || y >= S.hc) return;
  float acc[32];
  #pragma unroll
  for (int oc = 0; oc < 32; ++oc) acc[oc] = 0.f;
  #pragma unroll
  for (int ky = 0; ky < 3; ++ky)
    #pragma unroll
    for (int kx = 0; kx < 3; ++kx) {
      float v[16];
      #pragma unroll
      for (int ic = 0; ic < 16; ++ic) v[ic] = sh[(ic*6 + ty + ky)*66 + tx + kx];
      #pragma unroll
      for (int oc = 0; oc < 32; ++oc) {
        float tt = 0.f;
        #pragma unroll
        for (int ic = 0; ic < 16; ++ic)
          tt += v[ic] * w3[((oc*16 + ic)*3 + ky)*3 + kx];
        acc[oc] += tt;
      }
    }
  float l0 = 0.f, l1 = 0.f, r0 = 0.f, r1 = 0.f, r2v = 0.f, r3 = 0.f;
  #pragma unroll
  for (int oc = 0; oc < 32; ++oc) {
    float vv = acc[oc] + b3[oc];
    vv = vv > 0.f ? vv : a3[oc]*vv;
    l0 += vv * w41[oc];      l1 += vv * w41[32 + oc];
    r0 += vv * w42[oc];      r1 += vv * w42[32 + oc];
    r2v += vv * w42[64 + oc]; r3 += vv * w42[96 + oc];
  }
  l0 += b41[0]; l1 += b41[1];
  r0 += b42[0]; r1 += b42[1]; r2v += b42[2]; r3 += b42[3];
  float mx = fmaxf(l0, l1);
  float e0 = expf(l0 - mx), e1 = expf(l1 - mx);
  float score = e1 / (e0 + e1);
  float kv = (score >= 0.6f) ? score : -INFINITY;
  int local = (b*S.hc + y)*S.wc + x;
  keys[S.nk_off + local] = makekey(kv, (unsigned)local);
  reg4[S.nk_off + local] = make_float4(r0, r1, r2v, r3);
}

// ---------------- bitonic sort (4096, descending) in LDS ----------------
__device__ inline void bitonic4096_desc(u64* sh) {
  for (int kk = 2; kk <= 4096; kk <<= 1)
    for (int j = kk >> 1; j > 0; j >>= 1) {
      __syncthreads();
      for (int i = threadIdx.x; i < 4096; i += 256) {
        int ixj = i ^ j;
        if (ixj > i) {
          u64 a = sh[i], b = sh[ixj];
          if (((i & kk) == 0) ? (a < b) : (a > b)) { sh[i] = b; sh[ixj] = a; }
        }
      }
    }
  __syncthreads();
}

// ---------------- 5. hierarchical top-k reduce ----------------
__global__ __launch_bounds__(256) void k_topk_reduce(const u64* __restrict__ b0,
    const u64* __restrict__ b1, const u64* __restrict__ b2, const u64* __restrict__ b3,
    u64* __restrict__ outb, RedArgs ra) {
  __shared__ u64 sh[4096];
  int blk = blockIdx.x, ei = 0;
  while (ei + 1 < ra.ne && blk >= ra.e[ei].blk_start + ra.e[ei].nblk) ++ei;
  RedEnt e = ra.e[ei];
  int chunk = blk - e.blk_start;
  const u64* in = (e.in_buf == 0 ? b0 : e.in_buf == 1 ? b1 : e.in_buf == 2 ? b2 : b3)
                  + e.in_off + (size_t)chunk*4096;
  int m = e.n - chunk*4096; if (m > 4096) m = 4096;
  for (int i = threadIdx.x; i < 4096; i += 256) sh[i] = (i < m) ? in[i] : 0ULL;
  bitonic4096_desc(sh);
  u64* o = outb + e.out_off + (size_t)chunk * ra.outk;
  for (int i = threadIdx.x; i < ra.outk; i += 256) o[i] = sh[i];
}

// ---------------- 6. final per-scale sort + candidate gather ----------------
__global__ __launch_bounds__(256) void k_final_gather(const u64* __restrict__ b0,
    const u64* __restrict__ b1, const u64* __restrict__ b2,
    const float4* __restrict__ reg4, float* __restrict__ cb9, int* __restrict__ cinds,
    FinArgs fa) {
  __shared__ u64 sh[4096];
  FinEnt f = fa.e[blockIdx.x];
  const u64* in = (f.in_buf == 0 ? b0 : f.in_buf == 1 ? b1 : b2) + f.in_off;
  for (int i = threadIdx.x; i < 4096; i += 256) sh[i] = (i < f.n) ? in[i] : 0ULL;
  bitonic4096_desc(sh);
  for (int i = threadIdx.x; i < f.k; i += 256) {
    u64 c = sh[i];
    float val = keyval(c);
    unsigned idx = ~(unsigned)c;
    int x = (int)(idx % (unsigned)f.wc); unsigned t2 = idx / (unsigned)f.wc;
    int y = (int)(t2 % (unsigned)f.hc); int b = (int)(t2 / (unsigned)f.hc);
    float cx = (float)x, cy = (float)y;
    float x1 = floorf((2.0f*cx + 1.0f)/f.scf);
    float y1 = floorf((2.0f*cy + 1.0f)/f.scf);
    float x2 = floorf((2.0f*cx + 12.0f)/f.scf);
    float y2 = floorf((2.0f*cy + 12.0f)/f.scf);
    float4 rg = reg4[f.nk_off + idx];
    int g = f.cand_base + i;
    float* p = cb9 + (size_t)g*9;
    p[0]=x1; p[1]=y1; p[2]=x2; p[3]=y2; p[4]=val;
    p[5]=rg.x; p[6]=rg.y; p[7]=rg.z; p[8]=rg.w;
    cinds[g] = b;
  }
}

// ---------------- 7. per-scale greedy NMS (1 wave / scale) ----------------
__global__ __launch_bounds__(64) void k_nms_scale(const float* __restrict__ cb9,
    const int* __restrict__ cinds, u64* __restrict__ candk, NmsArgs na) {
  __shared__ float sx1[1024], sy1[1024], sx2[1024], sy2[1024], sar[1024], ssc[1024];
  int s = blockIdx.x, base = na.base[s], k = na.kk[s];
  int lane = threadIdx.x;
  for (int j = lane; j < k; j += 64) {
    const float* p = cb9 + (size_t)(base + j)*9;
    float off = OFFC * (float)cinds[base + j];
    float a = p[0] + off, b = p[1] + off, c = p[2] + off, d = p[3] + off;
    sx1[j]=a; sy1[j]=b; sx2[j]=c; sy2[j]=d;
    sar[j] = (c - a + 1.0f) * (d - b + 1.0f);
    ssc[j] = p[4];
  }
  __syncthreads();
  unsigned sup = 0, kept = 0;
  for (int i = 0; i < k; ++i) {
    int owner = i & 63, bit = i >> 6;
    unsigned so = (unsigned)__shfl((int)sup, owner);
    bool keep_i = (ssc[i] != -INFINITY) && !((so >> bit) & 1u);
    if (keep_i) {
      if (lane == owner) kept |= 1u << bit;
      float xi1 = sx1[i], yi1 = sy1[i], xi2 = sx2[i], yi2 = sy2[i], ai = sar[i];
      #pragma unroll
      for (int t = 0; t < 16; ++t) {
        int j = t*64 + lane;
        if (j > i && j < k) {
          float iw = fminf(xi2, sx2[j]) - fmaxf(xi1, sx1[j]) + 1.0f; iw = fmaxf(iw, 0.0f);
          float ih = fminf(yi2, sy2[j]) - fmaxf(yi1, sy1[j]) + 1.0f; ih = fmaxf(ih, 0.0f);
          float inter = iw*ih;
          if (inter / (ai + sar[j] - inter) > 0.5f) sup |= 1u << t;
        }
      }
    }
  }
  for (int t = 0; t < 16; ++t) {
    int j = t*64 + lane;
    if (j < k) {
      float v = ((kept >> t) & 1u) ? ssc[j] : -INFINITY;
      candk[base + j] = makekey(v, (unsigned)(base + j));
    }
  }
}

// ---------------- 8. global final sort (4096 -> top 2048) ----------------
__global__ __launch_bounds__(256) void k_gfinal(const u64* __restrict__ in, u64* __restrict__ gs) {
  __shared__ u64 sh[4096];
  for (int i = threadIdx.x; i < 4096; i += 256) sh[i] = in[i];
  bitonic4096_desc(sh);
  for (int i = threadIdx.x; i < KG; i += 256) gs[i] = sh[i];
}

// ---------------- 9. global greedy NMS (thresh 0.7) ----------------
__global__ __launch_bounds__(64) void k_nms_global(const u64* __restrict__ gs,
    const float* __restrict__ cb9, const int* __restrict__ cinds, int* __restrict__ gkeep) {
  __shared__ float sx1[KG], sy1[KG], sx2[KG], sy2[KG], sar[KG], ssc[KG];
  int lane = threadIdx.x;
  for (int j = lane; j < KG; j += 64) {
    u64 c = gs[j];
    unsigned g = ~(unsigned)c;
    const float* p = cb9 + (size_t)g*9;
    float off = OFFC * (float)cinds[g];
    float a = p[0] + off, b = p[1] + off, cc = p[2] + off, d = p[3] + off;
    sx1[j]=a; sy1[j]=b; sx2[j]=cc; sy2[j]=d;
    sar[j] = (cc - a + 1.0f) * (d - b + 1.0f);
    ssc[j] = keyval(c);
  }
  __syncthreads();
  unsigned sup = 0, kept = 0;
  for (int i = 0; i < KG; ++i) {
    int owner = i & 63, bit = i >> 6;
    unsigned so = (unsigned)__shfl((int)sup, owner);
    bool keep_i = (ssc[i] != -INFINITY) && !((so >> bit) & 1u);
    if (keep_i) {
      if (lane == owner) kept |= 1u << bit;
      float xi1 = sx1[i], yi1 = sy1[i], xi2 = sx2[i], yi2 = sy2[i], ai = sar[i];
      #pragma unroll
      for (int t = 0; t < 32; ++t) {
        int j = t*64 + lane;
        if (j > i) {
          float iw = fminf(xi2, sx2[j]) - fmaxf(xi1, sx1[j]) + 1.0f; iw = fmaxf(iw, 0.0f);
          float ih = fminf(yi2, sy2[j]) - fmaxf(yi1, sy1[j]) + 1.0f; ih = fmaxf(ih, 0.0f);
          float inter = iw*ih;
          if (inter / (ai + sar[j] - inter) > 0.7f) sup |= 1u << t;
        }
      }
    }
  }
  for (int t = 0; t < 32; ++t) { int j = t*64 + lane; gkeep[j] = (int)((kept >> t) & 1u); }
}

// ---------------- 10. refinement + output ----------------
__global__ __launch_bounds__(256) void k_finalize(const u64* __restrict__ gs,
    const int* __restrict__ gkeep, const float* __restrict__ cb9, const int* __restrict__ cinds,
    float* __restrict__ out) {
  int r = blockIdx.x*256 + threadIdx.x;
  if (r >= KG) return;
  u64 c = gs[r];
  unsigned g = ~(unsigned)c;
  float val = keyval(c);
  const float* p = cb9 + (size_t)g*9;
  int ind = cinds[g];
  bool valid = (val != -INFINITY) && (gkeep[r] != 0);
  float b0=p[0], b1v=p[1], b2v=p[2], b3=p[3], sc=p[4], r5=p[5], r6=p[6], r7=p[7], r8=p[8];
  float regw = b2v - b0, regh = b3 - b1v;
  float qq1 = b0 + r5*regw, qq2 = b1v + r6*regh, qq3 = b2v + r7*regw, qq4 = b3 + r8*regh;
  float bw = qq3 - qq1, bh = qq4 - qq2;
  float l = fmaxf(bw, bh);
  float x1n = qq1 + bw*0.5f - l*0.5f;
  float y1n = qq2 + bh*0.5f - l*0.5f;
  float o0 = x1n, o1 = y1n, o2 = x1n + l, o3 = y1n + l, o4 = sc;
  if (!valid) { o0=o1=o2=o3=o4=0.f; }
  out[r*5+0]=o0; out[r*5+1]=o1; out[r*5+2]=o2; out[r*5+3]=o3; out[r*5+4]=o4;
  out[5*KG + r] = valid ? 1.0f : 0.0f;
  out[6*KG + r] = (float)ind;
}

// ---------------- host ----------------
extern "C" void kernel_launch(void* const* d_in, const int* in_sizes, int n_in,
                              void* d_out, int out_size, void* d_ws, size_t ws_size,
                              hipStream_t stream) {
  (void)in_sizes; (void)n_in; (void)out_size;
  const float* imgs = (const float*)d_in[0];
  const float* c1w  = (const float*)d_in[1];
  const float* c1b  = (const float*)d_in[2];
  const float* a1   = (const float*)d_in[3];
  const float* c2w  = (const float*)d_in[4];
  const float* c2b  = (const float*)d_in[5];
  const float* a2   = (const float*)d_in[6];
  const float* c3w  = (const float*)d_in[7];
  const float* c3b  = (const float*)d_in[8];
  const float* a3   = (const float*)d_in[9];
  const float* c41w = (const float*)d_in[10];
  const float* c41b = (const float*)d_in[11];
  const float* c42w = (const float*)d_in[12];
  const float* c42b = (const float*)d_in[13];
  float* out = (float*)d_out;

  // scale pyramid, exactly mirroring the Python double-precision loop
  int ns = 0; double scl[MAXS];
  { double mm = 12.0/20.0; double minl = 720.0*mm; double ss = mm;
    while (minl >= 12.0 && ns < MAXS) { scl[ns++] = ss; ss *= 0.709; minl *= 0.709; } }

  PAll P{}; P.ns = ns;
  int tot_img=0, tot_pool=0, tot_c2=0, tot_n=0, tot_k=0;
  P.blkC1[0]=P.blkC2[0]=P.blkH[0]=0;
  for (int i = 0; i < ns; ++i) {
    SInfo& S = P.s[i];
    S.oh = (int)(720.0*scl[i] + 1.0); S.ow = (int)(1280.0*scl[i] + 1.0);
    int h1 = S.oh-2, w1 = S.ow-2;
    S.hp = (h1+1)/2; S.wp = (w1+1)/2;
    S.h2 = S.hp-2; S.w2 = S.wp-2;
    S.hc = S.hp-4; S.wc = S.wp-4;
    S.n = NB*S.hc*S.wc;
    S.k = S.n < 1024 ? S.n : 1024;
    S.scf = (float)scl[i];
    S.img_off = tot_img;   tot_img  += NB*3*S.oh*S.ow;
    S.pool_off = tot_pool; tot_pool += NB*10*S.hp*S.wp;
    S.c2_off = tot_c2;     tot_c2   += NB*16*S.h2*S.w2;
    S.nk_off = tot_n;      tot_n    += S.n;
    S.cand_base = tot_k;   tot_k    += S.k;
    S.g1x = (S.wp + 63)/64; S.g1y = (S.hp + 3)/4;
    S.g2x = (S.w2 + 63)/64; S.g2y = (S.h2 + 3)/4;
    S.g3x = (S.wc + 63)/64; S.g3y = (S.hc + 3)/4;
    P.blkC1[i+1] = P.blkC1[i] + S.g1x*S.g1y*NB;
    P.blkC2[i+1] = P.blkC2[i] + S.g2x*S.g2y*NB;
    P.blkH[i+1]  = P.blkH[i]  + S.g3x*S.g3y*NB;
  }

  // fixed per-scale regions in reduce ping-pong buffers
  int regA[MAXS] = {0}, regB[MAXS] = {0};
  long offA = 0, offB = 0;
  for (int i = 0; i < ns; ++i) {
    if (P.s[i].n > 4096) {
      int nb = (P.s[i].n + 4095)/4096;
      regA[i] = (int)offA; offA += (long)nb*1024;
      int n1 = nb*1024;
      if (n1 > 4096) { int nb1 = (n1 + 4095)/4096; regB[i] = (int)offB; offB += (long)nb1*1024; }
    }
  }
  long redAe = offA > 6144 ? offA : 6144;
  long redBe = offB > 4096 ? offB : 4096;

  // workspace layout
  char* wsb = (char*)d_ws; size_t wo = 0;
  auto take = [&](size_t bytes)->size_t { size_t r = wo; wo += (bytes + 255) & ~(size_t)255; return r; };
  float*  rsz    = (float*) (wsb + take((size_t)tot_img*4));
  float*  poolb  = (float*) (wsb + take((size_t)tot_pool*4));
  float*  c2buf  = (float*) (wsb + take((size_t)tot_c2*4));
  float4* reg4   = (float4*)(wsb + take((size_t)tot_n*16));
  u64*    keys   = (u64*)   (wsb + take((size_t)tot_n*8));
  u64*    redA   = (u64*)   (wsb + take((size_t)redAe*8));
  u64*    redB   = (u64*)   (wsb + take((size_t)redBe*8));
  float*  cb9    = (float*) (wsb + take((size_t)tot_k*9*4));
  int*    cinds  = (int*)   (wsb + take((size_t)tot_k*4));
  u64*    candk  = (u64*)   (wsb + take((size_t)tot_k*8));
  u64*    gsort  = (u64*)   (wsb + take((size_t)KG*8));
  int*    gkeep  = (int*)   (wsb + take((size_t)KG*4));

  // row-pool intermediate: aliases c2buf (written only later, at k_conv2 stage)
  size_t rowp_need = (size_t)NB*3*P.s[0].oh*IW*4;
  float* rowp = ((size_t)tot_c2*4 >= rowp_need) ? c2buf
              : (float*)(wsb + take(rowp_need));
  if (wo > ws_size) return;  // insufficient workspace

  // --- resize: two-pass separable (per scale, reusing rowp) ---
  for (int i = 0; i < ns; ++i) {
    const SInfo& S = P.s[i];
    int t1 = NB*3*S.oh*IW;
    int t2 = NB*3*S.oh*S.ow;
    k_rrows<<<(t1 + 255)/256, 256, 0, stream>>>(imgs, rowp, S.oh);
    k_rcols<<<(t2 + 255)/256, 256, 0, stream>>>(rowp, rsz, S.ow, S.img_off, t2);
  }

  k_conv1pool_t <<<P.blkC1[ns], 256, 0, stream>>>(rsz, c1w, c1b, a1, poolb, P);
  k_conv2_t     <<<P.blkC2[ns], 256, 0, stream>>>(poolb, c2w, c2b, a2, c2buf, P);
  k_conv3heads_t<<<P.blkH[ns],  256, 0, stream>>>(c2buf, c3w, c3b, a3, c41w, c41b, c42w, c42b,
                                                  keys, reg4, P);

  // per-scale hierarchical top-k
  struct Cur { int buf, off, n; } cur[MAXS];
  for (int i = 0; i < ns; ++i) { cur[i].buf = 0; cur[i].off = P.s[i].nk_off; cur[i].n = P.s[i].n; }
  for (int stage = 0; ; ++stage) {
    RedArgs ra{}; ra.ne = 0; ra.outk = 1024; int tb = 0;
    int ob = (stage & 1) ? 2 : 1;
    for (int i = 0; i < ns; ++i) if (cur[i].n > 4096) {
      int nb = (cur[i].n + 4095)/4096;
      RedEnt& e = ra.e[ra.ne++];
      e.in_buf = cur[i].buf; e.in_off = cur[i].off; e.n = cur[i].n;
      e.blk_start = tb; e.nblk = nb;
      e.out_off = (ob == 1) ? regA[i] : regB[i];
      tb += nb;
      cur[i].buf = ob; cur[i].off = e.out_off; cur[i].n = nb*1024;
    }
    if (!ra.ne) break;
    k_topk_reduce<<<tb, 256, 0, stream>>>(keys, redA, redB, candk,
                                          (ob == 1) ? redA : redB, ra);
  }

  FinArgs fa{};
  for (int i = 0; i < ns; ++i) {
    FinEnt& f = fa.e[i];
    f.in_buf = cur[i].buf; f.in_off = cur[i].off; f.n = cur[i].n;
    f.k = P.s[i].k; f.hc = P.s[i].hc; f.wc = P.s[i].wc;
    f.cand_base = P.s[i].cand_base; f.nk_off = P.s[i].nk_off; f.scf = P.s[i].scf;
  }
  k_final_gather<<<ns, 256, 0, stream>>>(keys, redA, redB, reg4, cb9, cinds, fa);

  NmsArgs na{};
  for (int i = 0; i < ns; ++i) { na.base[i] = P.s[i].cand_base; na.kk[i] = P.s[i].k; }
  k_nms_scale<<<ns, 64, 0, stream>>>(cb9, cinds, candk, na);

  // global top-2048: candk -> redA -> redB -> gsort
  {
    int nb1 = (tot_k + 4095)/4096;
    RedArgs ra{}; ra.ne = 1; ra.outk = KG;
    ra.e[0].in_buf = 3; ra.e[0].in_off = 0; ra.e[0].n = tot_k;
    ra.e[0].blk_start = 0; ra.e[0].nblk = nb1; ra.e[0].out_off = 0;
    k_topk_reduce<<<nb1, 256, 0, stream>>>(keys, redA, redB, candk, redA, ra);
    int n2 = nb1*KG;
    int nb2 = (n2 + 4095)/4096;
    RedArgs rb{}; rb.ne = 1; rb.outk = KG;
    rb.e[0].in_buf = 1; rb.e[0].in_off = 0; rb.e[0].n = n2;
    rb.e[0].blk_start = 0; rb.e[0].nblk = nb2; rb.e[0].out_off = 0;
    k_topk_reduce<<<nb2, 256, 0, stream>>>(keys, redA, redB, candk, redB, rb);
  }
  k_gfinal    <<<1, 256, 0, stream>>>(redB, gsort);
  k_nms_global<<<1, 64,  0, stream>>>(gsort, cb9, cinds, gkeep);
  k_finalize  <<<(KG + 255)/256, 256, 0, stream>>>(gsort, gkeep, cb9, cinds, out);
}